// Round 1
// baseline (340.302 us; speedup 1.0000x reference)
//
#include <hip/hip_runtime.h>

// TableEmbed3D: trilinear grid_sample of a [64, 32,32,32] fp32 table at 1e6
// points, align_corners=False, padding_mode='zeros'.
//
// Strategy:
//  1) transpose table [E=64, S=32768] -> [S, E] in d_ws so each spatial corner
//     holds its 64 channels contiguously (256 B).
//  2) main kernel: 16 lanes per point, each lane owns 4 channels (float4).
//     8 corner gathers per point are 256 B coalesced chunks; output stores are
//     fully coalesced (wave writes 1 KiB contiguous).

constexpr int TSZ = 32;
constexpr int S   = TSZ * TSZ * TSZ;  // 32768 spatial cells
constexpr int EMB = 64;               // channels

// ---------------------------------------------------------------------------
// Transpose [EMB, S] -> [S, EMB] via 64x64 LDS tiles (+1 pad, conflict-free).
// grid: S/64 blocks of 256 threads.
__global__ __launch_bounds__(256) void transpose_table_k(
    const float* __restrict__ tab, float* __restrict__ tabT) {
  __shared__ float tile[EMB][EMB + 1];
  const int s_base = blockIdx.x * 64;
  const int t  = threadIdx.x;
  const int c0 = t & 63;   // inner (coalesced) index
  const int r0 = t >> 6;   // 0..3
#pragma unroll
  for (int i = 0; i < 16; ++i) {
    const int e = r0 + 4 * i;
    tile[e][c0] = tab[(size_t)e * S + (s_base + c0)];  // coalesced read
  }
  __syncthreads();
#pragma unroll
  for (int i = 0; i < 16; ++i) {
    const int s = r0 + 4 * i;
    tabT[(size_t)(s_base + s) * EMB + c0] = tile[c0][s];  // coalesced write
  }
}

// ---------------------------------------------------------------------------
// Main kernel: 16 threads per point, each thread computes 4 channels.
__global__ __launch_bounds__(256) void embed_k(
    const float* __restrict__ x, const float4* __restrict__ tabT,
    float4* __restrict__ out, int n) {
  const int gid = blockIdx.x * 256 + threadIdx.x;
  const int pt  = gid >> 4;
  if (pt >= n) return;
  const int cg = gid & 15;  // channel group (4 channels each)

  // clip to [-1,1] then align_corners=False pixel mapping:
  // pix = ((g + 1) * 32 - 1) / 2
  const float gx = fminf(fmaxf(x[3 * pt + 0], -1.f), 1.f);
  const float gy = fminf(fmaxf(x[3 * pt + 1], -1.f), 1.f);
  const float gz = fminf(fmaxf(x[3 * pt + 2], -1.f), 1.f);
  const float px = ((gx + 1.f) * 32.f - 1.f) * 0.5f;
  const float py = ((gy + 1.f) * 32.f - 1.f) * 0.5f;
  const float pz = ((gz + 1.f) * 32.f - 1.f) * 0.5f;

  const float fxf = floorf(px), fyf = floorf(py), fzf = floorf(pz);
  const int ix0 = (int)fxf, iy0 = (int)fyf, iz0 = (int)fzf;
  const float fx = px - fxf, fy = py - fyf, fz = pz - fzf;
  const float wx[2] = {1.f - fx, fx};
  const float wy[2] = {1.f - fy, fy};
  const float wz[2] = {1.f - fz, fz};

  float4 acc = make_float4(0.f, 0.f, 0.f, 0.f);
#pragma unroll
  for (int dz = 0; dz < 2; ++dz) {
    const int  iz  = iz0 + dz;
    const bool bz  = (unsigned)iz < (unsigned)TSZ;
    const int  izc = min(max(iz, 0), TSZ - 1);
#pragma unroll
    for (int dy = 0; dy < 2; ++dy) {
      const int  iy  = iy0 + dy;
      const bool by  = (unsigned)iy < (unsigned)TSZ;
      const int  iyc = min(max(iy, 0), TSZ - 1);
#pragma unroll
      for (int dx = 0; dx < 2; ++dx) {
        const int  ix  = ix0 + dx;
        const bool bx  = (unsigned)ix < (unsigned)TSZ;
        const int  ixc = min(max(ix, 0), TSZ - 1);
        float w = wz[dz] * wy[dy] * wx[dx];
        w = (bx && by && bz) ? w : 0.f;  // zeros padding
        const int lin = (izc * TSZ + iyc) * TSZ + ixc;
        const float4 v = tabT[lin * (EMB / 4) + cg];
        acc.x = fmaf(w, v.x, acc.x);
        acc.y = fmaf(w, v.y, acc.y);
        acc.z = fmaf(w, v.z, acc.z);
        acc.w = fmaf(w, v.w, acc.w);
      }
    }
  }
  out[(size_t)pt * (EMB / 4) + cg] = acc;
}

// ---------------------------------------------------------------------------
// Fallback (workspace too small for the transposed table): 1 thread per
// (point, channel), reads original [E, S] layout. Slow but correct.
__global__ __launch_bounds__(256) void embed_fallback_k(
    const float* __restrict__ x, const float* __restrict__ tab,
    float* __restrict__ out, int n) {
  const int gid = blockIdx.x * 256 + threadIdx.x;
  const int pt  = gid >> 6;
  if (pt >= n) return;
  const int e = gid & 63;

  const float gx = fminf(fmaxf(x[3 * pt + 0], -1.f), 1.f);
  const float gy = fminf(fmaxf(x[3 * pt + 1], -1.f), 1.f);
  const float gz = fminf(fmaxf(x[3 * pt + 2], -1.f), 1.f);
  const float px = ((gx + 1.f) * 32.f - 1.f) * 0.5f;
  const float py = ((gy + 1.f) * 32.f - 1.f) * 0.5f;
  const float pz = ((gz + 1.f) * 32.f - 1.f) * 0.5f;

  const float fxf = floorf(px), fyf = floorf(py), fzf = floorf(pz);
  const int ix0 = (int)fxf, iy0 = (int)fyf, iz0 = (int)fzf;
  const float fx = px - fxf, fy = py - fyf, fz = pz - fzf;
  const float wx[2] = {1.f - fx, fx};
  const float wy[2] = {1.f - fy, fy};
  const float wz[2] = {1.f - fz, fz};

  float acc = 0.f;
#pragma unroll
  for (int dz = 0; dz < 2; ++dz) {
    const int  iz  = iz0 + dz;
    const bool bz  = (unsigned)iz < (unsigned)TSZ;
    const int  izc = min(max(iz, 0), TSZ - 1);
#pragma unroll
    for (int dy = 0; dy < 2; ++dy) {
      const int  iy  = iy0 + dy;
      const bool by  = (unsigned)iy < (unsigned)TSZ;
      const int  iyc = min(max(iy, 0), TSZ - 1);
#pragma unroll
      for (int dx = 0; dx < 2; ++dx) {
        const int  ix  = ix0 + dx;
        const bool bx  = (unsigned)ix < (unsigned)TSZ;
        const int  ixc = min(max(ix, 0), TSZ - 1);
        float w = wz[dz] * wy[dy] * wx[dx];
        w = (bx && by && bz) ? w : 0.f;
        const int lin = (izc * TSZ + iyc) * TSZ + ixc;
        acc = fmaf(w, tab[(size_t)e * S + lin], acc);
      }
    }
  }
  out[(size_t)pt * EMB + e] = acc;
}

// ---------------------------------------------------------------------------
extern "C" void kernel_launch(void* const* d_in, const int* in_sizes, int n_in,
                              void* d_out, int out_size, void* d_ws,
                              size_t ws_size, hipStream_t stream) {
  const float* x   = (const float*)d_in[0];
  const float* tab = (const float*)d_in[1];
  float*       out = (float*)d_out;
  const int n = in_sizes[0] / 3;

  const size_t need = (size_t)S * EMB * sizeof(float);  // 8 MiB
  if (ws_size >= need) {
    float* tabT = (float*)d_ws;
    transpose_table_k<<<S / 64, 256, 0, stream>>>(tab, tabT);
    const int total  = n * 16;  // 16 threads per point
    const int blocks = (total + 255) / 256;
    embed_k<<<blocks, 256, 0, stream>>>(x, (const float4*)tabT, (float4*)out, n);
  } else {
    const int total  = n * EMB;
    const int blocks = (total + 255) / 256;
    embed_fallback_k<<<blocks, 256, 0, stream>>>(x, tab, out, n);
  }
}

// Round 2
// 331.746 us; speedup vs baseline: 1.0258x; 1.0258x over previous
//
#include <hip/hip_runtime.h>

// TableEmbed3D: trilinear grid_sample of a [64, 32,32,32] fp32 table at 1e6
// points, align_corners=False, padding_mode='zeros'.
//
// R1 strategy:
//  1) transpose+quantize table [E=64, S=32768] fp32 -> [S, E] bf16 in d_ws.
//     4 MiB total -> fits a per-XCD L2 entirely; gather traffic halves.
//  2) main kernel: 16 lanes per point, each lane owns 4 channels (one uint2 =
//     4 bf16 per corner). Corner gathers are 128 B coalesced chunks; output
//     stores fp32 float4, wave writes 1 KiB contiguous.

constexpr int TSZ = 32;
constexpr int S   = TSZ * TSZ * TSZ;  // 32768 spatial cells
constexpr int EMB = 64;               // channels

__device__ __forceinline__ unsigned short f32_to_bf16_rne(float f) {
  unsigned int u = __float_as_uint(f);
  unsigned int lsb = (u >> 16) & 1u;
  u += 0x7FFFu + lsb;  // round to nearest even
  return (unsigned short)(u >> 16);
}

// ---------------------------------------------------------------------------
// Transpose [EMB, S] fp32 -> [S, EMB] bf16 via 64x64 LDS tiles (+1 pad).
// grid: S/64 blocks of 256 threads.
__global__ __launch_bounds__(256) void transpose_table_k(
    const float* __restrict__ tab, unsigned short* __restrict__ tabT) {
  __shared__ float tile[EMB][EMB + 1];
  const int s_base = blockIdx.x * 64;
  const int t  = threadIdx.x;
  const int c0 = t & 63;   // inner (coalesced) index
  const int r0 = t >> 6;   // 0..3
#pragma unroll
  for (int i = 0; i < 16; ++i) {
    const int e = r0 + 4 * i;
    tile[e][c0] = tab[(size_t)e * S + (s_base + c0)];  // coalesced read
  }
  __syncthreads();
#pragma unroll
  for (int i = 0; i < 16; ++i) {
    const int s = r0 + 4 * i;
    tabT[(size_t)(s_base + s) * EMB + c0] = f32_to_bf16_rne(tile[c0][s]);
  }
}

// ---------------------------------------------------------------------------
// Main kernel: 16 threads per point, each thread computes 4 channels.
// tabT is [S][64] bf16; one corner's 4 channels for lane cg = uint2 at
// (lin*64 + cg*4) ushorts == uint2 index lin*16 + cg.
__global__ __launch_bounds__(256) void embed_k(
    const float* __restrict__ x, const uint2* __restrict__ tabT,
    float4* __restrict__ out, int n) {
  const int gid = blockIdx.x * 256 + threadIdx.x;
  const int pt  = gid >> 4;
  if (pt >= n) return;
  const int cg = gid & 15;  // channel group (4 channels each)

  // clip to [-1,1] then align_corners=False pixel mapping:
  // pix = ((g + 1) * 32 - 1) / 2
  const float gx = fminf(fmaxf(x[3 * pt + 0], -1.f), 1.f);
  const float gy = fminf(fmaxf(x[3 * pt + 1], -1.f), 1.f);
  const float gz = fminf(fmaxf(x[3 * pt + 2], -1.f), 1.f);
  const float px = ((gx + 1.f) * 32.f - 1.f) * 0.5f;
  const float py = ((gy + 1.f) * 32.f - 1.f) * 0.5f;
  const float pz = ((gz + 1.f) * 32.f - 1.f) * 0.5f;

  const float fxf = floorf(px), fyf = floorf(py), fzf = floorf(pz);
  const int ix0 = (int)fxf, iy0 = (int)fyf, iz0 = (int)fzf;
  const float fx = px - fxf, fy = py - fyf, fz = pz - fzf;
  const float wx[2] = {1.f - fx, fx};
  const float wy[2] = {1.f - fy, fy};
  const float wz[2] = {1.f - fz, fz};

  float4 acc = make_float4(0.f, 0.f, 0.f, 0.f);
#pragma unroll
  for (int dz = 0; dz < 2; ++dz) {
    const int  iz  = iz0 + dz;
    const bool bz  = (unsigned)iz < (unsigned)TSZ;
    const int  izc = min(max(iz, 0), TSZ - 1);
#pragma unroll
    for (int dy = 0; dy < 2; ++dy) {
      const int  iy  = iy0 + dy;
      const bool by  = (unsigned)iy < (unsigned)TSZ;
      const int  iyc = min(max(iy, 0), TSZ - 1);
#pragma unroll
      for (int dx = 0; dx < 2; ++dx) {
        const int  ix  = ix0 + dx;
        const bool bx  = (unsigned)ix < (unsigned)TSZ;
        const int  ixc = min(max(ix, 0), TSZ - 1);
        float w = wz[dz] * wy[dy] * wx[dx];
        w = (bx && by && bz) ? w : 0.f;  // zeros padding
        const int lin = (izc * TSZ + iyc) * TSZ + ixc;
        const uint2 q = tabT[lin * 16 + cg];
        const float v0 = __uint_as_float(q.x << 16);
        const float v1 = __uint_as_float(q.x & 0xFFFF0000u);
        const float v2 = __uint_as_float(q.y << 16);
        const float v3 = __uint_as_float(q.y & 0xFFFF0000u);
        acc.x = fmaf(w, v0, acc.x);
        acc.y = fmaf(w, v1, acc.y);
        acc.z = fmaf(w, v2, acc.z);
        acc.w = fmaf(w, v3, acc.w);
      }
    }
  }
  out[(size_t)pt * (EMB / 4) + cg] = acc;
}

// ---------------------------------------------------------------------------
// Fallback (workspace too small): 1 thread per (point, channel), reads the
// original [E, S] fp32 layout. Slow but correct.
__global__ __launch_bounds__(256) void embed_fallback_k(
    const float* __restrict__ x, const float* __restrict__ tab,
    float* __restrict__ out, int n) {
  const int gid = blockIdx.x * 256 + threadIdx.x;
  const int pt  = gid >> 6;
  if (pt >= n) return;
  const int e = gid & 63;

  const float gx = fminf(fmaxf(x[3 * pt + 0], -1.f), 1.f);
  const float gy = fminf(fmaxf(x[3 * pt + 1], -1.f), 1.f);
  const float gz = fminf(fmaxf(x[3 * pt + 2], -1.f), 1.f);
  const float px = ((gx + 1.f) * 32.f - 1.f) * 0.5f;
  const float py = ((gy + 1.f) * 32.f - 1.f) * 0.5f;
  const float pz = ((gz + 1.f) * 32.f - 1.f) * 0.5f;

  const float fxf = floorf(px), fyf = floorf(py), fzf = floorf(pz);
  const int ix0 = (int)fxf, iy0 = (int)fyf, iz0 = (int)fzf;
  const float fx = px - fxf, fy = py - fyf, fz = pz - fzf;
  const float wx[2] = {1.f - fx, fx};
  const float wy[2] = {1.f - fy, fy};
  const float wz[2] = {1.f - fz, fz};

  float acc = 0.f;
#pragma unroll
  for (int dz = 0; dz < 2; ++dz) {
    const int  iz  = iz0 + dz;
    const bool bz  = (unsigned)iz < (unsigned)TSZ;
    const int  izc = min(max(iz, 0), TSZ - 1);
#pragma unroll
    for (int dy = 0; dy < 2; ++dy) {
      const int  iy  = iy0 + dy;
      const bool by  = (unsigned)iy < (unsigned)TSZ;
      const int  iyc = min(max(iy, 0), TSZ - 1);
#pragma unroll
      for (int dx = 0; dx < 2; ++dx) {
        const int  ix  = ix0 + dx;
        const bool bx  = (unsigned)ix < (unsigned)TSZ;
        const int  ixc = min(max(ix, 0), TSZ - 1);
        float w = wz[dz] * wy[dy] * wx[dx];
        w = (bx && by && bz) ? w : 0.f;
        const int lin = (izc * TSZ + iyc) * TSZ + ixc;
        acc = fmaf(w, tab[(size_t)e * S + lin], acc);
      }
    }
  }
  out[(size_t)pt * EMB + e] = acc;
}

// ---------------------------------------------------------------------------
extern "C" void kernel_launch(void* const* d_in, const int* in_sizes, int n_in,
                              void* d_out, int out_size, void* d_ws,
                              size_t ws_size, hipStream_t stream) {
  const float* x   = (const float*)d_in[0];
  const float* tab = (const float*)d_in[1];
  float*       out = (float*)d_out;
  const int n = in_sizes[0] / 3;

  const size_t need = (size_t)S * EMB * sizeof(unsigned short);  // 4 MiB
  if (ws_size >= need) {
    unsigned short* tabT = (unsigned short*)d_ws;
    transpose_table_k<<<S / 64, 256, 0, stream>>>(tab, tabT);
    const int total  = n * 16;  // 16 threads per point
    const int blocks = (total + 255) / 256;
    embed_k<<<blocks, 256, 0, stream>>>(x, (const uint2*)tabT, (float4*)out, n);
  } else {
    const int total  = n * EMB;
    const int blocks = (total + 255) / 256;
    embed_fallback_k<<<blocks, 256, 0, stream>>>(x, tab, out, n);
  }
}

// Round 4
// 319.695 us; speedup vs baseline: 1.0645x; 1.0377x over previous
//
#include <hip/hip_runtime.h>

// TableEmbed3D: trilinear grid_sample of a [64, 32,32,32] fp32 table at 1e6
// points, align_corners=False, padding_mode='zeros'.
//
// R4 strategy (R3 + compile fix for nontemporal store):
//  - table transposed+quantized to [S=32768][64] bf16 in d_ws (4 MiB, fits a
//    per-XCD L2).
//  - embed: 8 lanes per point, each lane owns 8 channels. Every corner gather
//    is one dense uint4 (16 B) load; 8 lanes cover the full 128 B row.
//    Wave-level: 1 KiB per load instruction, contiguous per point.
//  - nontemporal loads for x (streaming) and nontemporal stores for out so the
//    256 MB write stream doesn't evict the table from L2.

constexpr int TSZ = 32;
constexpr int S   = TSZ * TSZ * TSZ;  // 32768 spatial cells
constexpr int EMB = 64;               // channels

typedef float floatx4 __attribute__((ext_vector_type(4)));  // native vec for nt-store

__device__ __forceinline__ unsigned short f32_to_bf16_rne(float f) {
  unsigned int u = __float_as_uint(f);
  unsigned int lsb = (u >> 16) & 1u;
  u += 0x7FFFu + lsb;  // round to nearest even
  return (unsigned short)(u >> 16);
}

// ---------------------------------------------------------------------------
// Transpose [EMB, S] fp32 -> [S, EMB] bf16 via 64x64 LDS tiles (+1 pad).
// grid: S/64 blocks of 256 threads.
__global__ __launch_bounds__(256) void transpose_table_k(
    const float* __restrict__ tab, unsigned short* __restrict__ tabT) {
  __shared__ float tile[EMB][EMB + 1];
  const int s_base = blockIdx.x * 64;
  const int t  = threadIdx.x;
  const int c0 = t & 63;   // inner (coalesced) index
  const int r0 = t >> 6;   // 0..3
#pragma unroll
  for (int i = 0; i < 16; ++i) {
    const int e = r0 + 4 * i;
    tile[e][c0] = tab[(size_t)e * S + (s_base + c0)];  // coalesced read
  }
  __syncthreads();
#pragma unroll
  for (int i = 0; i < 16; ++i) {
    const int s = r0 + 4 * i;
    tabT[(size_t)(s_base + s) * EMB + c0] = f32_to_bf16_rne(tile[c0][s]);
  }
}

// ---------------------------------------------------------------------------
// Main kernel: 8 threads per point, each thread computes 8 channels.
// tabT viewed as uint4* : row lin occupies elements [lin*8 .. lin*8+7];
// lane c8 reads element lin*8 + c8 (16 B = 8 bf16 channels).
__global__ __launch_bounds__(256) void embed_k(
    const float* __restrict__ x, const uint4* __restrict__ tabT,
    float* __restrict__ out, int n) {
  const int gid = blockIdx.x * 256 + threadIdx.x;
  const int pt  = gid >> 3;
  if (pt >= n) return;
  const int c8 = gid & 7;  // channel octet (8 channels each)

  // clip to [-1,1] then align_corners=False pixel mapping:
  // pix = ((g + 1) * 32 - 1) / 2
  const float gx = fminf(fmaxf(__builtin_nontemporal_load(&x[3 * pt + 0]), -1.f), 1.f);
  const float gy = fminf(fmaxf(__builtin_nontemporal_load(&x[3 * pt + 1]), -1.f), 1.f);
  const float gz = fminf(fmaxf(__builtin_nontemporal_load(&x[3 * pt + 2]), -1.f), 1.f);
  const float px = ((gx + 1.f) * 32.f - 1.f) * 0.5f;
  const float py = ((gy + 1.f) * 32.f - 1.f) * 0.5f;
  const float pz = ((gz + 1.f) * 32.f - 1.f) * 0.5f;

  const float fxf = floorf(px), fyf = floorf(py), fzf = floorf(pz);
  const int ix0 = (int)fxf, iy0 = (int)fyf, iz0 = (int)fzf;
  const float fx = px - fxf, fy = py - fyf, fz = pz - fzf;
  const float wx[2] = {1.f - fx, fx};
  const float wy[2] = {1.f - fy, fy};
  const float wz[2] = {1.f - fz, fz};

  float acc[8];
#pragma unroll
  for (int k = 0; k < 8; ++k) acc[k] = 0.f;

#pragma unroll
  for (int dz = 0; dz < 2; ++dz) {
    const int  iz  = iz0 + dz;
    const bool bz  = (unsigned)iz < (unsigned)TSZ;
    const int  izc = min(max(iz, 0), TSZ - 1);
#pragma unroll
    for (int dy = 0; dy < 2; ++dy) {
      const int  iy  = iy0 + dy;
      const bool by  = (unsigned)iy < (unsigned)TSZ;
      const int  iyc = min(max(iy, 0), TSZ - 1);
      const int  rowbase = (izc * TSZ + iyc) * TSZ;
      const float wzy = wz[dz] * wy[dy];
#pragma unroll
      for (int dx = 0; dx < 2; ++dx) {
        const int  ix  = ix0 + dx;
        const bool bx  = (unsigned)ix < (unsigned)TSZ;
        const int  ixc = min(max(ix, 0), TSZ - 1);
        float w = wzy * wx[dx];
        w = (bx && by && bz) ? w : 0.f;  // zeros padding
        const int lin = rowbase + ixc;
        const uint4 q = tabT[lin * 8 + c8];
        const float v0 = __uint_as_float(q.x << 16);
        const float v1 = __uint_as_float(q.x & 0xFFFF0000u);
        const float v2 = __uint_as_float(q.y << 16);
        const float v3 = __uint_as_float(q.y & 0xFFFF0000u);
        const float v4 = __uint_as_float(q.z << 16);
        const float v5 = __uint_as_float(q.z & 0xFFFF0000u);
        const float v6 = __uint_as_float(q.w << 16);
        const float v7 = __uint_as_float(q.w & 0xFFFF0000u);
        acc[0] = fmaf(w, v0, acc[0]);
        acc[1] = fmaf(w, v1, acc[1]);
        acc[2] = fmaf(w, v2, acc[2]);
        acc[3] = fmaf(w, v3, acc[3]);
        acc[4] = fmaf(w, v4, acc[4]);
        acc[5] = fmaf(w, v5, acc[5]);
        acc[6] = fmaf(w, v6, acc[6]);
        acc[7] = fmaf(w, v7, acc[7]);
      }
    }
  }

  // out: point row = 64 floats; lane c8 owns floats [c8*8 .. c8*8+7].
  const floatx4 s0 = {acc[0], acc[1], acc[2], acc[3]};
  const floatx4 s1 = {acc[4], acc[5], acc[6], acc[7]};
  floatx4* dst = (floatx4*)(out + (size_t)pt * EMB + c8 * 8);
  __builtin_nontemporal_store(s0, &dst[0]);
  __builtin_nontemporal_store(s1, &dst[1]);
}

// ---------------------------------------------------------------------------
// Fallback (workspace too small): 1 thread per (point, channel), reads the
// original [E, S] fp32 layout. Slow but correct.
__global__ __launch_bounds__(256) void embed_fallback_k(
    const float* __restrict__ x, const float* __restrict__ tab,
    float* __restrict__ out, int n) {
  const int gid = blockIdx.x * 256 + threadIdx.x;
  const int pt  = gid >> 6;
  if (pt >= n) return;
  const int e = gid & 63;

  const float gx = fminf(fmaxf(x[3 * pt + 0], -1.f), 1.f);
  const float gy = fminf(fmaxf(x[3 * pt + 1], -1.f), 1.f);
  const float gz = fminf(fmaxf(x[3 * pt + 2], -1.f), 1.f);
  const float px = ((gx + 1.f) * 32.f - 1.f) * 0.5f;
  const float py = ((gy + 1.f) * 32.f - 1.f) * 0.5f;
  const float pz = ((gz + 1.f) * 32.f - 1.f) * 0.5f;

  const float fxf = floorf(px), fyf = floorf(py), fzf = floorf(pz);
  const int ix0 = (int)fxf, iy0 = (int)fyf, iz0 = (int)fzf;
  const float fx = px - fxf, fy = py - fyf, fz = pz - fzf;
  const float wx[2] = {1.f - fx, fx};
  const float wy[2] = {1.f - fy, fy};
  const float wz[2] = {1.f - fz, fz};

  float acc = 0.f;
#pragma unroll
  for (int dz = 0; dz < 2; ++dz) {
    const int  iz  = iz0 + dz;
    const bool bz  = (unsigned)iz < (unsigned)TSZ;
    const int  izc = min(max(iz, 0), TSZ - 1);
#pragma unroll
    for (int dy = 0; dy < 2; ++dy) {
      const int  iy  = iy0 + dy;
      const bool by  = (unsigned)iy < (unsigned)TSZ;
      const int  iyc = min(max(iy, 0), TSZ - 1);
#pragma unroll
      for (int dx = 0; dx < 2; ++dx) {
        const int  ix  = ix0 + dx;
        const bool bx  = (unsigned)ix < (unsigned)TSZ;
        const int  ixc = min(max(ix, 0), TSZ - 1);
        float w = wz[dz] * wy[dy] * wx[dx];
        w = (bx && by && bz) ? w : 0.f;
        const int lin = (izc * TSZ + iyc) * TSZ + ixc;
        acc = fmaf(w, tab[(size_t)e * S + lin], acc);
      }
    }
  }
  out[(size_t)pt * EMB + e] = acc;
}

// ---------------------------------------------------------------------------
extern "C" void kernel_launch(void* const* d_in, const int* in_sizes, int n_in,
                              void* d_out, int out_size, void* d_ws,
                              size_t ws_size, hipStream_t stream) {
  const float* x   = (const float*)d_in[0];
  const float* tab = (const float*)d_in[1];
  float*       out = (float*)d_out;
  const int n = in_sizes[0] / 3;

  const size_t need = (size_t)S * EMB * sizeof(unsigned short);  // 4 MiB
  if (ws_size >= need) {
    unsigned short* tabT = (unsigned short*)d_ws;
    transpose_table_k<<<S / 64, 256, 0, stream>>>(tab, tabT);
    const int total  = n * 8;  // 8 threads per point
    const int blocks = (total + 255) / 256;
    embed_k<<<blocks, 256, 0, stream>>>(x, (const uint4*)tabT, out, n);
  } else {
    const int total  = n * EMB;
    const int blocks = (total + 255) / 256;
    embed_fallback_k<<<blocks, 256, 0, stream>>>(x, tab, out, n);
  }
}